// Round 21
// baseline (3944.741 us; speedup 1.0000x reference)
//
#include <hip/hip_runtime.h>

using short8 = __attribute__((ext_vector_type(8))) short;
using f32x4  = __attribute__((ext_vector_type(4))) float;
using uint4v = __attribute__((ext_vector_type(4))) unsigned;

#define NT     512
#define NBATCH 64
#define NN     1024
#define NIN    24
#define NG     4                      // groups of 16 batches
#define ROWS   16
#define TILE32 (ROWS * NN)            // u32 per group tile
#define PARSTRIDE (NG * TILE32)       // u32 per parity buffer (256 KB)
#define SCOPE_AGENT __HIP_MEMORY_SCOPE_AGENT
#define RETRY_CAP (1 << 17)           // fail loud (absmax), never hang

#define KBSTRIDE 1280                 // bytes per kb-slice in LDS A-tile
#define ATILE_BYTES (32 * KBSTRIDE)   // 40 KB
#define PL_BYTES (64 * 64 * 16)       // 64 KB partial tile
#define LDS_TOTAL (ATILE_BYTES + PL_BYTES)

// R20 = R18's block-cooperative coalesced STAGING (proven load path) +
// R15/R19's K-SPLIT consumption (wave reads only its 4 kb-slices: 32 KB LDS
// reads/step vs R18's 256 KB + conflicts) + R18's clock pacing (T0 from the
// self-aligning init stage). Epoch-in-data sync throughout: no flags, no
// fences, no cache-maintenance ops; mis-pacing degrades to validated retry.

__device__ __forceinline__ unsigned short f2bf(float x) {
  union { float f; unsigned u; } v; v.f = x;
  return (unsigned short)((v.u + 0x7FFFu + ((v.u >> 16) & 1u)) >> 16);
}
__device__ __forceinline__ f32x4 MF(short8 a, short8 b, f32x4 c) {
  return __builtin_amdgcn_mfma_f32_16x16x32_bf16(a, b, c, 0, 0, 0);
}

#define PACKS8(dst, Rx, Ry) do { \
  union { unsigned u[4]; short8 s; } pk_; \
  pk_.u[0] = (Rx[0] & 0xFFFFu) | (Rx[1] << 16); \
  pk_.u[1] = (Rx[2] & 0xFFFFu) | (Rx[3] << 16); \
  pk_.u[2] = (Ry[0] & 0xFFFFu) | (Ry[1] << 16); \
  pk_.u[3] = (Ry[2] & 0xFFFFu) | (Ry[3] << 16); \
  dst = pk_.s; } while (0)

// 32 blocks x 512 thr (8 waves). Group g = bid&3 owns batches [16g,+16);
// slot = bid>>2 owns neurons [128*slot,+128). Wave w computes partials over
// K-slice [128w,+128) for all 8 col-sets, then owns output col-set w.
__global__ __launch_bounds__(512, 1) void rnn_step_all(
    const float* __restrict__ u, const float* __restrict__ r0,
    const float* __restrict__ W, const float* __restrict__ Bm,
    const float* __restrict__ tau, const float* __restrict__ ds,
    float* __restrict__ out, unsigned* __restrict__ obs32,
    unsigned long long P_ticks)
{
  extern __shared__ char dlds[];
  char* atile = dlds;                               // [kb 0..31][swizzled rows]
  f32x4 (*pl)[64] = (f32x4(*)[64])(dlds + ATILE_BYTES);  // [c*8+w][lane]

  const int tid  = threadIdx.x;
  const int wave = tid >> 6;
  const int lane = tid & 63;
  const int bid  = blockIdx.x;
  const int g    = bid & 3;
  const int slot = bid >> 2;
  const int b0   = g * ROWS;
  const int lr = lane & 15, lg = lane >> 4;
  const int i  = slot * 128 + wave * 16 + lr;   // OUTPUT neuron (col-set = wave)

  // loader assignment: thread covers row mrow, k in [mc*32, mc*32+32)
  const int mrow = tid >> 5;                    // 0..15
  const int mc   = tid & 31;                    // 0..31 (== kb it loads)

  // ---- W fragments: 8 col-sets x this wave's K-slice (128 VGPR) ----
  short8 wf[8][4];
#pragma unroll
  for (int c = 0; c < 8; ++c) {
#pragma unroll
    for (int j = 0; j < 4; ++j) {
      const int col = slot * 128 + c * 16 + lr;
      const int k0  = wave * 128 + j * 32 + lg * 8;
      f32x4 w0 = *(const f32x4*)(W + (size_t)col * NN + k0);
      f32x4 w1 = *(const f32x4*)(W + (size_t)col * NN + k0 + 4);
      f32x4 s0 = *(const f32x4*)(ds + k0);
      f32x4 s1 = *(const f32x4*)(ds + k0 + 4);
      short8 f;
      f[0]=(short)f2bf(w0[0]*s0[0]); f[1]=(short)f2bf(w0[1]*s0[1]);
      f[2]=(short)f2bf(w0[2]*s0[2]); f[3]=(short)f2bf(w0[3]*s0[3]);
      f[4]=(short)f2bf(w1[0]*s1[0]); f[5]=(short)f2bf(w1[1]*s1[1]);
      f[6]=(short)f2bf(w1[2]*s1[2]); f[7]=(short)f2bf(w1[3]*s1[3]);
      wf[c][j] = f;
    }
  }
  short8 bin;
#pragma unroll
  for (int e = 0; e < 8; ++e) {
    const int m = lg * 8 + e;
    bin[e] = (short)f2bf(m < NIN ? Bm[(size_t)i * NIN + m] : 0.0f);
  }
  const float itau = 1.0f / tau[i];

  unsigned* gt0 = obs32 + g * TILE32;              // parity-0 tile
  unsigned* gt1 = obs32 + PARSTRIDE + g * TILE32;  // parity-1 tile

  // stage: block-cooperative coalesced load + validate + kb-major LDS write.
  // Write addr: kb*1280 + (row*80 + e*16) ^ ((kb&7)<<4)  (both sides ~peak).
  auto stage = [&](const unsigned* gtile, unsigned tag) {
    const unsigned* gp = gtile + mrow * NN + mc * 32;
    uint4v R0,R1,R2,R3,R4,R5,R6,R7;
    int guard = 0;
    for (;;) {
      asm volatile(
          "global_load_dwordx4 %0, %8, off sc0 sc1\n\t"
          "global_load_dwordx4 %1, %8, off offset:16 sc0 sc1\n\t"
          "global_load_dwordx4 %2, %8, off offset:32 sc0 sc1\n\t"
          "global_load_dwordx4 %3, %8, off offset:48 sc0 sc1\n\t"
          "global_load_dwordx4 %4, %8, off offset:64 sc0 sc1\n\t"
          "global_load_dwordx4 %5, %8, off offset:80 sc0 sc1\n\t"
          "global_load_dwordx4 %6, %8, off offset:96 sc0 sc1\n\t"
          "global_load_dwordx4 %7, %8, off offset:112 sc0 sc1\n\t"
          "s_waitcnt vmcnt(0)"
          : "=&v"(R0), "=&v"(R1), "=&v"(R2), "=&v"(R3),
            "=&v"(R4), "=&v"(R5), "=&v"(R6), "=&v"(R7)
          : "v"(gp) : "memory");
      unsigned bad = 0;
#define CK(Rx) bad |= ((Rx[0]>>16)^tag) | ((Rx[1]>>16)^tag) | \
                      ((Rx[2]>>16)^tag) | ((Rx[3]>>16)^tag)
      CK(R0); CK(R1); CK(R2); CK(R3); CK(R4); CK(R5); CK(R6); CK(R7);
#undef CK
      if (__all((int)(bad == 0))) break;
      if (++guard > RETRY_CAP) break;   // fail loud, never hang
    }
    char* kbase = atile + mc * KBSTRIDE;
    const int swz = (mc & 7) << 4;
    short8 f;
    PACKS8(f, R0, R1); *(short8*)(kbase + ((mrow * 80 +  0) ^ swz)) = f;
    PACKS8(f, R2, R3); *(short8*)(kbase + ((mrow * 80 + 16) ^ swz)) = f;
    PACKS8(f, R4, R5); *(short8*)(kbase + ((mrow * 80 + 32) ^ swz)) = f;
    PACKS8(f, R6, R7); *(short8*)(kbase + ((mrow * 80 + 48) ^ swz)) = f;
  };

  // ---- init r (C/D: row=lg*4+q, col=lr); publish tag 1 into parity 0 ----
  f32x4 r;
#pragma unroll
  for (int q = 0; q < 4; ++q) {
    const int row = lg * 4 + q;
    r[q] = r0[(size_t)(b0 + row) * NN + i];
    __hip_atomic_store(&gt0[row * NN + i],
                       (unsigned)f2bf(fmaxf(r[q], 0.f)) | (1u << 16),
                       __ATOMIC_RELAXED, SCOPE_AGENT);
  }

  const float* ub = u + (size_t)(b0 + lr) * NT * NIN;
  f32x4 up0 = {0,0,0,0}, up1 = {0,0,0,0};
  if (lg < 3) {
    up0 = *(const f32x4*)(ub + lg * 8);
    up1 = *(const f32x4*)(ub + lg * 8 + 4);
  }

  stage(gt0, 1u);       // init exchange aligns all blocks to ~1 chain
  __syncthreads();
  const unsigned long long T0 = __builtin_amdgcn_s_memrealtime();

  for (int t = 0; t < NT; ++t) {
    const unsigned tag2 = (unsigned)(t + 2);
    unsigned* wrt = (t & 1) ? gt0 : gt1;
    const bool last = (t == NT - 1);

    // ---- A fragments from this wave's 4 kb-slices (32 KB total LDS reads) --
    short8 af0, af1, af2, af3;
    {
      const int ro = lr * 80 + lg * 16;
      const char* p0 = atile + (wave*4+0) * KBSTRIDE + (ro ^ (((wave*4+0)&7)<<4));
      const char* p1 = atile + (wave*4+1) * KBSTRIDE + (ro ^ (((wave*4+1)&7)<<4));
      const char* p2 = atile + (wave*4+2) * KBSTRIDE + (ro ^ (((wave*4+2)&7)<<4));
      const char* p3 = atile + (wave*4+3) * KBSTRIDE + (ro ^ (((wave*4+3)&7)<<4));
      af0 = *(const short8*)p0; af1 = *(const short8*)p1;
      af2 = *(const short8*)p2; af3 = *(const short8*)p3;
    }

    // ---- partial GEMM: 8 col-sets x 4 k-blocks (32 MFMA) ----
#pragma unroll
    for (int c = 0; c < 8; ++c) {
      f32x4 p = {0,0,0,0};
      p = MF(af0, wf[c][0], p);
      p = MF(af1, wf[c][1], p);
      p = MF(af2, wf[c][2], p);
      p = MF(af3, wf[c][3], p);
      pl[c * 8 + wave][lane] = p;
    }
    __syncthreads();   // BAR_a: partials ready; atile reads done

    f32x4 acc = pl[wave * 8 + 0][lane];
#pragma unroll
    for (int s = 1; s < 8; ++s)
      acc += pl[wave * 8 + s][lane];

    // ---- u-term folded in as one accumulate-MFMA (col-set = wave) ----
    short8 ua;
    ua[0]=(short)f2bf(up0[0]); ua[1]=(short)f2bf(up0[1]);
    ua[2]=(short)f2bf(up0[2]); ua[3]=(short)f2bf(up0[3]);
    ua[4]=(short)f2bf(up1[0]); ua[5]=(short)f2bf(up1[1]);
    ua[6]=(short)f2bf(up1[2]); ua[7]=(short)f2bf(up1[3]);
    if (lg >= 3) ua = short8{0,0,0,0,0,0,0,0};
    acc = MF(ua, bin, acc);

    // ---- state update (60*sigmoid(0.28x-8.4) via native exp2) ----
    f32x4 rv;
#pragma unroll
    for (int q = 0; q < 4; ++q) {
      const float act = 60.0f / (1.0f + exp2f(12.118664f - 0.40395462f * acc[q]));
      rv[q] = r[q] + (0.1f * (act - r[q])) * itau;
      r[q]  = rv[q];
    }

    if (!last) {
      // publish tagged obs immediately (fire-and-forget agent stores)
#pragma unroll
      for (int q = 0; q < 4; ++q)
        __hip_atomic_store(&wrt[(lg * 4 + q) * NN + i],
                           (unsigned)f2bf(fmaxf(rv[q], 0.f)) | (tag2 << 16),
                           __ATOMIC_RELAXED, SCOPE_AGENT);
    }

    // off-critical-path: out stores + u prefetch (publish flight covers them)
#pragma unroll
    for (int q = 0; q < 4; ++q)
      out[((size_t)(b0 + lg * 4 + q) * NT + t) * NN + i] = rv[q];
    if (!last && lg < 3) {
      const float* up = ub + (t + 1) * NIN + lg * 8;
      up0 = *(const f32x4*)(up);
      up1 = *(const f32x4*)(up + 4);
    }

    if (!last) {
      // pace: by T0+(t+1)P every block has published tag t+2
      const unsigned long long gate = T0 + (unsigned long long)(t + 1) * P_ticks;
      for (;;) {
        if (__builtin_amdgcn_s_memrealtime() >= gate) break;
        __builtin_amdgcn_s_sleep(2);
      }
      stage(wrt, tag2);   // one validated round in steady state
      __syncthreads();    // BAR_b: atile ready; pl reusable next step
    }
  }

  // r_final
  const size_t fbase = (size_t)NBATCH * NT * NN;
#pragma unroll
  for (int q = 0; q < 4; ++q)
    out[fbase + (size_t)(b0 + lg * 4 + q) * NN + i] = r[q];
}

extern "C" void kernel_launch(void* const* d_in, const int* in_sizes, int n_in,
                              void* d_out, int out_size, void* d_ws, size_t ws_size,
                              hipStream_t stream) {
  const float* u   = (const float*)d_in[0];
  const float* r0  = (const float*)d_in[1];
  const float* W   = (const float*)d_in[2];
  const float* Bm  = (const float*)d_in[3];
  const float* tau = (const float*)d_in[4];
  const float* ds  = (const float*)d_in[5];
  float* out = (float*)d_out;

  unsigned* obs32 = (unsigned*)d_ws;

  // allow >64KB dynamic LDS (deterministic, idempotent; not a stream op)
  hipFuncSetAttribute((const void*)rnn_step_all,
                      hipFuncAttributeMaxDynamicSharedMemorySize, LDS_TOTAL);

  // wall-clock rate (kHz) -> ticks per 2.4 us period; fallback 100 MHz RTC
  int wckhz = 0;
  if (hipDeviceGetAttribute(&wckhz, hipDeviceAttributeWallClockRate, 0)
          != hipSuccess || wckhz <= 0)
    wckhz = 100000;
  unsigned long long P_ticks =
      (unsigned long long)((2.4e-6) * (double)wckhz * 1000.0 + 0.5);
  if (P_ticks < 2) P_ticks = 2;

  // zero both epoch-tagged buffers every call (tags restart at 1 -> deterministic)
  hipMemsetAsync(d_ws, 0, 2 * PARSTRIDE * sizeof(unsigned), stream);

  rnn_step_all<<<dim3(32), dim3(512), LDS_TOTAL, stream>>>(u, r0, W, Bm, tau, ds,
                                                           out, obs32, P_ticks);
}

// Round 22
// 1834.111 us; speedup vs baseline: 2.1508x; 2.1508x over previous
//
#include <hip/hip_runtime.h>

using short8 = __attribute__((ext_vector_type(8))) short;
using f32x4  = __attribute__((ext_vector_type(4))) float;
using uint4v = __attribute__((ext_vector_type(4))) unsigned;

#define NT     512
#define NBATCH 64
#define NN     1024
#define NIN    24
#define NG     4                      // groups of 16 batches
#define ROWS   16
#define TILE32 (ROWS * NN)            // u32 per group tile
#define PARSTRIDE (NG * TILE32)       // u32 per parity buffer (256 KB)
#define SCOPE_AGENT __HIP_MEMORY_SCOPE_AGENT
#define RETRY_CAP (1 << 17)           // fail loud (absmax), never hang

#define ATILE_BYTES (ROWS * 2048)     // 32 KB row-major swizzled A-tile (R18 layout)
#define PL_BYTES (64 * 64 * 16)       // 64 KB partial-exchange tile
#define LDS_TOTAL (ATILE_BYTES + PL_BYTES)

// R21 = R18 (best: 1676us; coalesced block-cooperative stage + clock pacing)
// with K-SPLIT consumption: R18's stage layout ALREADY partitions K per wave
// (thread (mrow,mc) writes k-spans [128m+4mc,+4) row-major, XOR-swizzled), so
// wave w reads only its K-slice [128w,+128) (4 instead of 64 reads/lane),
// computes partials for all 8 col-sets, and exchanges through the R15-proven
// conflict-free pl tile. LDS/step: 544 KB -> ~190 KB; chain ~1.5-1.8us.
// Epoch-in-data sync throughout; mis-pacing degrades to validated retry.

__device__ __forceinline__ unsigned short f2bf(float x) {
  union { float f; unsigned u; } v; v.f = x;
  return (unsigned short)((v.u + 0x7FFFu + ((v.u >> 16) & 1u)) >> 16);
}
__device__ __forceinline__ f32x4 MF(short8 a, short8 b, f32x4 c) {
  return __builtin_amdgcn_mfma_f32_16x16x32_bf16(a, b, c, 0, 0, 0);
}

// 32 blocks x 512 thr (8 waves). Group g = bid&3 owns batches [16g,+16);
// slot = bid>>2 owns neurons [128*slot,+128). Wave w computes partials over
// K-slice [128w,+128) for all 8 col-sets, then owns output col-set w.
__global__ __launch_bounds__(512, 1) void rnn_step_all(
    const float* __restrict__ u, const float* __restrict__ r0,
    const float* __restrict__ W, const float* __restrict__ Bm,
    const float* __restrict__ tau, const float* __restrict__ ds,
    float* __restrict__ out, unsigned* __restrict__ obs32,
    unsigned long long P_ticks)
{
  extern __shared__ char dlds[];
  char* ldsb = dlds;                                     // A-tile (R18 layout)
  f32x4 (*pl)[64] = (f32x4(*)[64])(dlds + ATILE_BYTES);  // [c*8+w][lane]

  const int tid  = threadIdx.x;
  const int wave = tid >> 6;
  const int lane = tid & 63;
  const int bid  = blockIdx.x;
  const int g    = bid & 3;
  const int slot = bid >> 2;
  const int b0   = g * ROWS;
  const int lr = lane & 15, lg = lane >> 4;
  const int i  = slot * 128 + wave * 16 + lr;   // OUTPUT neuron (col-set = wave)

  // loader assignment (R18): thread covers row mrow, u32 cols [4*mc + 128*m]
  const int mrow = tid >> 5;                    // 0..15
  const int mc   = tid & 31;                    // 0..31

  // ---- W fragments: 8 col-sets x this wave's K-slice (128 VGPR) ----
  short8 wf[8][4];
#pragma unroll
  for (int c = 0; c < 8; ++c) {
#pragma unroll
    for (int j = 0; j < 4; ++j) {
      const int col = slot * 128 + c * 16 + lr;
      const int k0  = wave * 128 + j * 32 + lg * 8;
      f32x4 w0 = *(const f32x4*)(W + (size_t)col * NN + k0);
      f32x4 w1 = *(const f32x4*)(W + (size_t)col * NN + k0 + 4);
      f32x4 s0 = *(const f32x4*)(ds + k0);
      f32x4 s1 = *(const f32x4*)(ds + k0 + 4);
      short8 f;
      f[0]=(short)f2bf(w0[0]*s0[0]); f[1]=(short)f2bf(w0[1]*s0[1]);
      f[2]=(short)f2bf(w0[2]*s0[2]); f[3]=(short)f2bf(w0[3]*s0[3]);
      f[4]=(short)f2bf(w1[0]*s1[0]); f[5]=(short)f2bf(w1[1]*s1[1]);
      f[6]=(short)f2bf(w1[2]*s1[2]); f[7]=(short)f2bf(w1[3]*s1[3]);
      wf[c][j] = f;
    }
  }
  short8 bin;
#pragma unroll
  for (int e = 0; e < 8; ++e) {
    const int m = lg * 8 + e;
    bin[e] = (short)f2bf(m < NIN ? Bm[(size_t)i * NIN + m] : 0.0f);
  }
  const float itau = 1.0f / tau[i];

  unsigned* gt0 = obs32 + g * TILE32;              // parity-0 tile
  unsigned* gt1 = obs32 + PARSTRIDE + g * TILE32;  // parity-1 tile

  // stage (R18 VERBATIM): coalesced tagged load + validate + swizzled write
  auto stage = [&](const unsigned* gtile, unsigned tag) {
    const unsigned* gp = gtile + mrow * NN + mc * 4;
    uint4v R0, R1, R2, R3, R4, R5, R6, R7;
    int guard = 0;
    for (;;) {
      asm volatile(
          "global_load_dwordx4 %0, %8, off sc0 sc1\n\t"
          "global_load_dwordx4 %1, %8, off offset:512 sc0 sc1\n\t"
          "global_load_dwordx4 %2, %8, off offset:1024 sc0 sc1\n\t"
          "global_load_dwordx4 %3, %8, off offset:1536 sc0 sc1\n\t"
          "global_load_dwordx4 %4, %8, off offset:2048 sc0 sc1\n\t"
          "global_load_dwordx4 %5, %8, off offset:2560 sc0 sc1\n\t"
          "global_load_dwordx4 %6, %8, off offset:3072 sc0 sc1\n\t"
          "global_load_dwordx4 %7, %8, off offset:3584 sc0 sc1\n\t"
          "s_waitcnt vmcnt(0)"
          : "=&v"(R0), "=&v"(R1), "=&v"(R2), "=&v"(R3),
            "=&v"(R4), "=&v"(R5), "=&v"(R6), "=&v"(R7)
          : "v"(gp) : "memory");
      unsigned bad = 0;
#define CK(Rx) bad |= ((Rx[0] >> 16) ^ tag) | ((Rx[1] >> 16) ^ tag) | \
                      ((Rx[2] >> 16) ^ tag) | ((Rx[3] >> 16) ^ tag)
      CK(R0); CK(R1); CK(R2); CK(R3); CK(R4); CK(R5); CK(R6); CK(R7);
#undef CK
      if (__all((int)(bad == 0))) break;
      if (++guard > RETRY_CAP) break;   // fail loud, never hang
    }
    const int rbm = (mrow & 7) << 4;
    char* wrow = ldsb + mrow * 2048;
#define WR(Rx, m) do { \
      unsigned lo = (Rx[0] & 0xFFFFu) | (Rx[1] << 16); \
      unsigned hi = (Rx[2] & 0xFFFFu) | (Rx[3] << 16); \
      *(unsigned long long*)(wrow + (((m) * 256 + 8 * mc) ^ rbm)) = \
          ((unsigned long long)hi << 32) | (unsigned long long)lo; \
    } while (0)
    WR(R0, 0); WR(R1, 1); WR(R2, 2); WR(R3, 3);
    WR(R4, 4); WR(R5, 5); WR(R6, 6); WR(R7, 7);
#undef WR
  };

  // ---- init r (C/D: row=lg*4+q, col=lr); publish tag 1 into parity 0 ----
  f32x4 r;
#pragma unroll
  for (int q = 0; q < 4; ++q) {
    const int row = lg * 4 + q;
    r[q] = r0[(size_t)(b0 + row) * NN + i];
    __hip_atomic_store(&gt0[row * NN + i],
                       (unsigned)f2bf(fmaxf(r[q], 0.f)) | (1u << 16),
                       __ATOMIC_RELAXED, SCOPE_AGENT);
  }

  const float* ub = u + (size_t)(b0 + lr) * NT * NIN;
  f32x4 up0 = {0,0,0,0}, up1 = {0,0,0,0};
  if (lg < 3) {
    up0 = *(const f32x4*)(ub + lg * 8);
    up1 = *(const f32x4*)(ub + lg * 8 + 4);
  }

  stage(gt0, 1u);       // init exchange aligns all blocks
  __syncthreads();
  const unsigned long long T0 = __builtin_amdgcn_s_memrealtime();

  const char* lrow = ldsb + lr * 2048;
  const int rbc = (lr & 7) << 4;

  for (int t = 0; t < NT; ++t) {
    const unsigned tag2 = (unsigned)(t + 2);
    unsigned* wrt = (t & 1) ? gt0 : gt1;
    const bool last = (t == NT - 1);

    // ---- A fragments: this wave's K-slice only (4 x short8 per lane) ----
    // byte offset of k: 2*k = wave*256 + kb'*64 + lg*16, XOR (lr&7)<<4
    short8 af0, af1, af2, af3;
    {
      const int base = wave * 256 + lg * 16;
      af0 = *(const short8*)(lrow + ((base +   0) ^ rbc));
      af1 = *(const short8*)(lrow + ((base +  64) ^ rbc));
      af2 = *(const short8*)(lrow + ((base + 128) ^ rbc));
      af3 = *(const short8*)(lrow + ((base + 192) ^ rbc));
    }

    // ---- partial GEMM: 8 col-sets x 4 k-blocks (32 MFMA) ----
#pragma unroll
    for (int c = 0; c < 8; ++c) {
      f32x4 p = {0,0,0,0};
      p = MF(af0, wf[c][0], p);
      p = MF(af1, wf[c][1], p);
      p = MF(af2, wf[c][2], p);
      p = MF(af3, wf[c][3], p);
      pl[c * 8 + wave][lane] = p;
    }
    __syncthreads();   // BAR_a: partials ready; atile reads done

    f32x4 acc = pl[wave * 8 + 0][lane];
#pragma unroll
    for (int s = 1; s < 8; ++s)
      acc += pl[wave * 8 + s][lane];

    // ---- u-term folded in as one accumulate-MFMA (col-set = wave) ----
    short8 ua;
    ua[0]=(short)f2bf(up0[0]); ua[1]=(short)f2bf(up0[1]);
    ua[2]=(short)f2bf(up0[2]); ua[3]=(short)f2bf(up0[3]);
    ua[4]=(short)f2bf(up1[0]); ua[5]=(short)f2bf(up1[1]);
    ua[6]=(short)f2bf(up1[2]); ua[7]=(short)f2bf(up1[3]);
    if (lg >= 3) ua = short8{0,0,0,0,0,0,0,0};
    acc = MF(ua, bin, acc);

    // ---- state update (60*sigmoid(0.28x-8.4) via native exp2) ----
    f32x4 rv;
#pragma unroll
    for (int q = 0; q < 4; ++q) {
      const float act = 60.0f / (1.0f + exp2f(12.118664f - 0.40395462f * acc[q]));
      rv[q] = r[q] + (0.1f * (act - r[q])) * itau;
      r[q]  = rv[q];
    }

    if (!last) {
      // publish tagged obs immediately (fire-and-forget agent stores)
#pragma unroll
      for (int q = 0; q < 4; ++q)
        __hip_atomic_store(&wrt[(lg * 4 + q) * NN + i],
                           (unsigned)f2bf(fmaxf(rv[q], 0.f)) | (tag2 << 16),
                           __ATOMIC_RELAXED, SCOPE_AGENT);
    }

    // off-critical-path: out stores + u prefetch (publish flight covers them)
#pragma unroll
    for (int q = 0; q < 4; ++q)
      out[((size_t)(b0 + lg * 4 + q) * NT + t) * NN + i] = rv[q];
    if (!last && lg < 3) {
      const float* up = ub + (t + 1) * NIN + lg * 8;
      up0 = *(const f32x4*)(up);
      up1 = *(const f32x4*)(up + 4);
    }

    if (!last) {
      // pace: by T0+(t+1)P every block has published tag t+2
      const unsigned long long gate = T0 + (unsigned long long)(t + 1) * P_ticks;
      for (;;) {
        if (__builtin_amdgcn_s_memrealtime() >= gate) break;
        __builtin_amdgcn_s_sleep(2);
      }
      stage(wrt, tag2);   // one validated round in steady state
      __syncthreads();    // BAR_b: atile ready; pl reusable next step
    }
  }

  // r_final
  const size_t fbase = (size_t)NBATCH * NT * NN;
#pragma unroll
  for (int q = 0; q < 4; ++q)
    out[fbase + (size_t)(b0 + lg * 4 + q) * NN + i] = r[q];
}

extern "C" void kernel_launch(void* const* d_in, const int* in_sizes, int n_in,
                              void* d_out, int out_size, void* d_ws, size_t ws_size,
                              hipStream_t stream) {
  const float* u   = (const float*)d_in[0];
  const float* r0  = (const float*)d_in[1];
  const float* W   = (const float*)d_in[2];
  const float* Bm  = (const float*)d_in[3];
  const float* tau = (const float*)d_in[4];
  const float* ds  = (const float*)d_in[5];
  float* out = (float*)d_out;

  unsigned* obs32 = (unsigned*)d_ws;

  // allow >64KB dynamic LDS (deterministic, idempotent; not a stream op)
  hipFuncSetAttribute((const void*)rnn_step_all,
                      hipFuncAttributeMaxDynamicSharedMemorySize, LDS_TOTAL);

  // wall-clock rate (kHz) -> ticks per 2.2 us period; fallback 100 MHz RTC
  int wckhz = 0;
  if (hipDeviceGetAttribute(&wckhz, hipDeviceAttributeWallClockRate, 0)
          != hipSuccess || wckhz <= 0)
    wckhz = 100000;
  unsigned long long P_ticks =
      (unsigned long long)((2.2e-6) * (double)wckhz * 1000.0 + 0.5);
  if (P_ticks < 2) P_ticks = 2;

  // zero both epoch-tagged buffers every call (tags restart at 1 -> deterministic)
  hipMemsetAsync(d_ws, 0, 2 * PARSTRIDE * sizeof(unsigned), stream);

  rnn_step_all<<<dim3(32), dim3(512), LDS_TOTAL, stream>>>(u, r0, W, Bm, tau, ds,
                                                           out, obs32, P_ticks);
}